// Round 3
// baseline (291.364 us; speedup 1.0000x reference)
//
#include <hip/hip_runtime.h>
#include <hip/hip_bf16.h>
#include <stdint.h>

#define Bb 32
#define Ss 512
#define Ee 512
#define Hh 8
#define Dd 64
#define EPSf 1e-5f

typedef __attribute__((ext_vector_type(8))) unsigned short ushort8_t;
typedef __attribute__((ext_vector_type(4))) unsigned short ushort4_t;
typedef __attribute__((ext_vector_type(4))) float f32x4;
typedef __attribute__((ext_vector_type(4))) unsigned int uint4_t;
typedef __attribute__((ext_vector_type(8))) __bf16 bf16x8;

union U8cast { ushort8_t u; bf16x8 b; uint4_t w; };
__device__ __forceinline__ bf16x8 as_bf16x8(ushort8_t u) { U8cast c; c.u = u; return c.b; }
__device__ __forceinline__ bf16x8 words_bf16x8(unsigned int w0, unsigned int w1,
                                               unsigned int w2, unsigned int w3) {
  U8cast c; c.w = (uint4_t){w0, w1, w2, w3}; return c.b;
}

__device__ __forceinline__ unsigned short f2bf(float f) {
  __bf16 b = (__bf16)f;                 // RNE fptrunc
  return __builtin_bit_cast(unsigned short, b);
}
__device__ __forceinline__ unsigned int pack2bf(float lo, float hi) {
  return ((unsigned int)f2bf(hi) << 16) | f2bf(lo);
}

__device__ __forceinline__ f32x4 mfma16(bf16x8 a, bf16x8 b, f32x4 c) {
  return __builtin_amdgcn_mfma_f32_16x16x32_bf16(a, b, c, 0, 0, 0);
}

__device__ __forceinline__ void async16(const unsigned short* g, unsigned short* l) {
  __builtin_amdgcn_global_load_lds(
      (const __attribute__((address_space(1))) void*)g,
      (__attribute__((address_space(3))) void*)l, 16, 0, 0);
}

// ---------------- fp32 -> bf16 convert ----------------
__global__ __launch_bounds__(256) void cvt_bf16(const float* __restrict__ src,
                                                unsigned short* __restrict__ dst, int n8) {
  int i = blockIdx.x * 256 + threadIdx.x;
  int stride = gridDim.x * 256;
  for (; i < n8; i += stride) {
    float4 v0 = ((const float4*)src)[2 * i];
    float4 v1 = ((const float4*)src)[2 * i + 1];
    ushort8_t o;
    o[0] = f2bf(v0.x); o[1] = f2bf(v0.y); o[2] = f2bf(v0.z); o[3] = f2bf(v0.w);
    o[4] = f2bf(v1.x); o[5] = f2bf(v1.y); o[6] = f2bf(v1.z); o[7] = f2bf(v1.w);
    ((ushort8_t*)dst)[i] = o;
  }
}

// ---------------- QKV projection: MFMA bf16 ----------------
// C[m][n] = sum_k Xb[m][k] * Wb[n][k] + bin[n];  M=16384, N=1536, K=512
// scatter: Q,K -> [B*H][S][D]; V -> Vt [B*H][D][S] (transposed for PV's A-operand)
__global__ __launch_bounds__(256) void qkv_mm(
    const unsigned short* __restrict__ Xb, const unsigned short* __restrict__ Wb,
    const float* __restrict__ bin,
    unsigned short* __restrict__ Qo, unsigned short* __restrict__ Ko,
    unsigned short* __restrict__ Vto) {
  __shared__ unsigned short As[128 * 64];
  __shared__ unsigned short Bs[128 * 64];
  const int tid = threadIdx.x;
  const int w = tid >> 6, l = tid & 63;
  const int lr = l & 15, lg = l >> 4;
  const int m0 = blockIdx.y * 128, n0 = blockIdx.x * 128;
  const int wm = (w >> 1) * 64, wn = (w & 1) * 64;
  f32x4 acc[4][4];
#pragma unroll
  for (int i = 0; i < 4; ++i)
#pragma unroll
    for (int j = 0; j < 4; ++j) acc[i][j] = (f32x4){0.f, 0.f, 0.f, 0.f};

  for (int k0 = 0; k0 < 512; k0 += 64) {
    // stage 128x64 A and B tiles; source pre-swizzled so LDS stays linear (G21)
#pragma unroll
    for (int i = 0; i < 4; ++i) {
      int ci = (w * 4 + i) * 64 + l;         // 16B-chunk index
      int row = ci >> 3, kc = ci & 7;
      int gkc = kc ^ (row & 7);
      async16(Xb + (size_t)(m0 + row) * 512 + k0 + gkc * 8, &As[(w * 4 + i) * 512]);
      async16(Wb + (size_t)(n0 + row) * 512 + k0 + gkc * 8, &Bs[(w * 4 + i) * 512]);
    }
    __syncthreads();
#pragma unroll
    for (int ks = 0; ks < 2; ++ks) {
      bf16x8 af[4], bfr[4];
#pragma unroll
      for (int mf = 0; mf < 4; ++mf) {
        int row = wm + mf * 16 + lr;
        int gc = ks * 4 + lg;
        af[mf] = as_bf16x8(*(const ushort8_t*)&As[row * 64 + ((gc ^ (row & 7)) * 8)]);
      }
#pragma unroll
      for (int nf = 0; nf < 4; ++nf) {
        int row = wn + nf * 16 + lr;
        int gc = ks * 4 + lg;
        bfr[nf] = as_bf16x8(*(const ushort8_t*)&Bs[row * 64 + ((gc ^ (row & 7)) * 8)]);
      }
#pragma unroll
      for (int mf = 0; mf < 4; ++mf)
#pragma unroll
        for (int nf = 0; nf < 4; ++nf) acc[mf][nf] = mfma16(af[mf], bfr[nf], acc[mf][nf]);
    }
    __syncthreads();
  }

#pragma unroll
  for (int nf = 0; nf < 4; ++nf) {
    int n = n0 + wn + nf * 16 + lr;
    float bias = bin[n];
    int which = n >> 9, e = n & 511, h = e >> 6, d = e & 63;
#pragma unroll
    for (int mf = 0; mf < 4; ++mf) {
#pragma unroll
      for (int r = 0; r < 4; ++r) {
        int m = m0 + wm + mf * 16 + lg * 4 + r;
        int bb = m >> 9, s = m & 511;
        unsigned short val = f2bf(acc[mf][nf][r] + bias);
        if (which == 0)
          Qo[(((size_t)(bb * Hh + h)) * Ss + s) * Dd + d] = val;
        else if (which == 1)
          Ko[(((size_t)(bb * Hh + h)) * Ss + s) * Dd + d] = val;
        else
          Vto[(((size_t)(bb * Hh + h)) * Dd + d) * Ss + s] = val;
      }
    }
  }
}

// ---------------- fused attention (register-only) ----------------
// block: one (b,h), 64 q-rows; 4 waves x 16 q-rows each. No LDS.
// Swapped QK^T: C=P[k][q]. K-rows permuted into A-frags so that frag pair
// (2c,2c+1) holds exactly the 8 consecutive k PV's B-operand needs per lane.
__global__ __launch_bounds__(256) void attn_fused(
    const unsigned short* __restrict__ Q, const unsigned short* __restrict__ K,
    const unsigned short* __restrict__ Vt, float* __restrict__ att,
    unsigned short* __restrict__ Zb) {
  const int tid = threadIdx.x;
  const int w = tid >> 6, l = tid & 63;
  const int lr = l & 15, lg = l >> 4;
  const int bh = blockIdx.y;
  const int b = bh >> 3, h = bh & 7;
  const int m0 = blockIdx.x * 64;
  const unsigned short* Qp = Q + (size_t)bh * Ss * Dd;
  const unsigned short* Kp = K + (size_t)bh * Ss * Dd;
  const unsigned short* Vp = Vt + (size_t)bh * Dd * Ss;   // [64][512]

  const int q0g = m0 + w * 16;
  // Q as B-operand: lane holds Q[q0g+lr][lg*8+j], two d-halves
  bf16x8 bq0 = as_bf16x8(*(const ushort8_t*)(Qp + (size_t)(q0g + lr) * Dd + lg * 8));
  bf16x8 bq1 = as_bf16x8(*(const ushort8_t*)(Qp + (size_t)(q0g + lr) * Dd + 32 + lg * 8));

  // permuted K-row base for A-frags: frag nf=(2c+odd), A-row lr -> K row
  // 32c + 8*(lr>>2) + 4*odd + (lr&3); C elem (lg,r) -> k = 32c + 8lg + 4odd + r
  const int krow = 8 * (lr >> 2) + (lr & 3);

  f32x4 sc[32];
#pragma unroll
  for (int nf = 0; nf < 32; ++nf) {
    int c = nf >> 1, odd = nf & 1;
    int row = 32 * c + 4 * odd + krow;
    bf16x8 ak0 = as_bf16x8(*(const ushort8_t*)(Kp + (size_t)row * Dd + lg * 8));
    bf16x8 ak1 = as_bf16x8(*(const ushort8_t*)(Kp + (size_t)row * Dd + 32 + lg * 8));
    f32x4 z = (f32x4){0.f, 0.f, 0.f, 0.f};
    z = mfma16(ak0, bq0, z);
    sc[nf] = mfma16(ak1, bq1, z);
  }

  // ---- softmax over k for q=lr (values spread over frags x r x 4 lg-lanes)
  float mx = sc[0][0];
#pragma unroll
  for (int nf = 0; nf < 32; ++nf)
#pragma unroll
    for (int r = 0; r < 4; ++r) mx = fmaxf(mx, sc[nf][r]);
  mx = fmaxf(mx, __shfl_xor(mx, 16));
  mx = fmaxf(mx, __shfl_xor(mx, 32));
  float ssum = 0.f;
#pragma unroll
  for (int nf = 0; nf < 32; ++nf)
#pragma unroll
    for (int r = 0; r < 4; ++r) {
      float p = __expf((sc[nf][r] - mx) * 0.125f);
      sc[nf][r] = p;
      ssum += p;
    }
  ssum += __shfl_xor(ssum, 16);
  ssum += __shfl_xor(ssum, 32);
  float inv = 1.0f / ssum;
#pragma unroll
  for (int nf = 0; nf < 32; ++nf)
#pragma unroll
    for (int r = 0; r < 4; ++r) sc[nf][r] *= inv;

  // ---- write att_w: per chunk c, lane covers k = 32c+8lg .. +7 (fp32)
  float* attp = att + (size_t)bh * Ss * Ss + (size_t)(q0g + lr) * Ss;
#pragma unroll
  for (int c = 0; c < 16; ++c) {
    *(f32x4*)(attp + 32 * c + 8 * lg) = sc[2 * c];
    *(f32x4*)(attp + 32 * c + 8 * lg + 4) = sc[2 * c + 1];
  }

  // ---- PV: A = Vt frags (rows d), B = P built in-register from frag pairs
  f32x4 o[4];
#pragma unroll
  for (int df = 0; df < 4; ++df) o[df] = (f32x4){0.f, 0.f, 0.f, 0.f};
#pragma unroll
  for (int c = 0; c < 16; ++c) {
    bf16x8 bp = words_bf16x8(pack2bf(sc[2 * c][0], sc[2 * c][1]),
                             pack2bf(sc[2 * c][2], sc[2 * c][3]),
                             pack2bf(sc[2 * c + 1][0], sc[2 * c + 1][1]),
                             pack2bf(sc[2 * c + 1][2], sc[2 * c + 1][3]));
#pragma unroll
    for (int df = 0; df < 4; ++df) {
      bf16x8 av = as_bf16x8(
          *(const ushort8_t*)(Vp + (size_t)(df * 16 + lr) * Ss + 32 * c + lg * 8));
      o[df] = mfma16(av, bp, o[df]);
    }
  }

  // ---- Z (merged heads) bf16: C[d][q] -> lane writes 4 consecutive d (8B)
  unsigned short* zrow = Zb + ((size_t)(b * Ss) + q0g + lr) * Ee + h * Dd;
#pragma unroll
  for (int df = 0; df < 4; ++df) {
    ushort4_t zz;
    zz[0] = f2bf(o[df][0]); zz[1] = f2bf(o[df][1]);
    zz[2] = f2bf(o[df][2]); zz[3] = f2bf(o[df][3]);
    *(ushort4_t*)(zrow + df * 16 + lg * 4) = zz;
  }
}

// ---------------- out projection: MFMA bf16 + bias + residual ----------------
// y[m][n] = sum_k Zb[m][k]*Wout[n][k] + bout[n] + X[m][n]; M=16384, N=512, K=512
__global__ __launch_bounds__(256) void out_mm(
    const unsigned short* __restrict__ Zb, const unsigned short* __restrict__ Wb,
    const float* __restrict__ bout, const float* __restrict__ X,
    float* __restrict__ Y) {
  __shared__ unsigned short As[128 * 64];
  __shared__ unsigned short Bs[128 * 64];
  const int tid = threadIdx.x;
  const int w = tid >> 6, l = tid & 63;
  const int lr = l & 15, lg = l >> 4;
  const int m0 = blockIdx.y * 128, n0 = blockIdx.x * 128;
  const int wm = (w >> 1) * 64, wn = (w & 1) * 64;
  f32x4 acc[4][4];
#pragma unroll
  for (int i = 0; i < 4; ++i)
#pragma unroll
    for (int j = 0; j < 4; ++j) acc[i][j] = (f32x4){0.f, 0.f, 0.f, 0.f};

  for (int k0 = 0; k0 < 512; k0 += 64) {
#pragma unroll
    for (int i = 0; i < 4; ++i) {
      int ci = (w * 4 + i) * 64 + l;
      int row = ci >> 3, kc = ci & 7;
      int gkc = kc ^ (row & 7);
      async16(Zb + (size_t)(m0 + row) * 512 + k0 + gkc * 8, &As[(w * 4 + i) * 512]);
      async16(Wb + (size_t)(n0 + row) * 512 + k0 + gkc * 8, &Bs[(w * 4 + i) * 512]);
    }
    __syncthreads();
#pragma unroll
    for (int ks = 0; ks < 2; ++ks) {
      bf16x8 af[4], bfr[4];
#pragma unroll
      for (int mf = 0; mf < 4; ++mf) {
        int row = wm + mf * 16 + lr;
        int gc = ks * 4 + lg;
        af[mf] = as_bf16x8(*(const ushort8_t*)&As[row * 64 + ((gc ^ (row & 7)) * 8)]);
      }
#pragma unroll
      for (int nf = 0; nf < 4; ++nf) {
        int row = wn + nf * 16 + lr;
        int gc = ks * 4 + lg;
        bfr[nf] = as_bf16x8(*(const ushort8_t*)&Bs[row * 64 + ((gc ^ (row & 7)) * 8)]);
      }
#pragma unroll
      for (int mf = 0; mf < 4; ++mf)
#pragma unroll
        for (int nf = 0; nf < 4; ++nf) acc[mf][nf] = mfma16(af[mf], bfr[nf], acc[mf][nf]);
    }
    __syncthreads();
  }

#pragma unroll
  for (int nf = 0; nf < 4; ++nf) {
    int n = n0 + wn + nf * 16 + lr;
    float bias = bout[n];
#pragma unroll
    for (int mf = 0; mf < 4; ++mf) {
#pragma unroll
      for (int r = 0; r < 4; ++r) {
        int m = m0 + wm + mf * 16 + lg * 4 + r;
        Y[(size_t)m * 512 + n] = acc[mf][nf][r] + bias + X[(size_t)m * 512 + n];
      }
    }
  }
}

// ---------------- LayerNorm (in place on y region) ----------------
__global__ __launch_bounds__(128) void ln_kernel(
    const float* __restrict__ Z2, const float* __restrict__ gamma,
    const float* __restrict__ beta, float* __restrict__ Y) {
  const int row = blockIdx.x;
  const int t = threadIdx.x;
  float4 v = *(const float4*)(Z2 + (size_t)row * 512 + t * 4);
  float sum = v.x + v.y + v.z + v.w;
  float sq = v.x * v.x + v.y * v.y + v.z * v.z + v.w * v.w;
#pragma unroll
  for (int off = 32; off; off >>= 1) {
    sum += __shfl_xor(sum, off);
    sq += __shfl_xor(sq, off);
  }
  __shared__ float s0[2], s1[2];
  int wv = t >> 6;
  if ((t & 63) == 0) { s0[wv] = sum; s1[wv] = sq; }
  __syncthreads();
  sum = s0[0] + s0[1];
  sq = s1[0] + s1[1];
  float mu = sum * (1.0f / 512.0f);
  float var = sq * (1.0f / 512.0f) - mu * mu;
  float rs = rsqrtf(var + EPSf);
  float4 g = *(const float4*)(gamma + t * 4);
  float4 be = *(const float4*)(beta + t * 4);
  float4 o;
  o.x = (v.x - mu) * rs * g.x + be.x;
  o.y = (v.y - mu) * rs * g.y + be.y;
  o.z = (v.z - mu) * rs * g.z + be.z;
  o.w = (v.w - mu) * rs * g.w + be.w;
  *(float4*)(Y + (size_t)row * 512 + t * 4) = o;
}

extern "C" void kernel_launch(void* const* d_in, const int* in_sizes, int n_in,
                              void* d_out, int out_size, void* d_ws, size_t ws_size,
                              hipStream_t stream) {
  const float* x = (const float*)d_in[0];
  const float* w_in = (const float*)d_in[1];
  const float* b_in = (const float*)d_in[2];
  const float* w_out = (const float*)d_in[3];
  const float* b_out = (const float*)d_in[4];
  const float* gamma = (const float*)d_in[5];
  const float* beta = (const float*)d_in[6];

  float* y = (float*)d_out;                                   // [B,S,E] fp32
  float* att = (float*)d_out + (size_t)Bb * Ss * Ee;          // [B,H,S,S] fp32

  char* ws = (char*)d_ws;
  const size_t NBH = (size_t)Bb * Hh * Ss * Dd;               // 8.39M elems
  unsigned short* Q     = (unsigned short*)ws;                // 16.78 MB
  unsigned short* Kb    = Q + NBH;
  unsigned short* Vtb   = Kb + NBH;                           // [BH][D][S]
  unsigned short* xb    = Vtb + NBH;                          // [16384][512] bf16
  unsigned short* Zb    = xb;                                 // alias: xb dead after qkv_mm
  unsigned short* winb  = xb + NBH;                           // [1536][512]
  unsigned short* woutb = winb + (size_t)3 * Ee * Ee;         // [512][512]

  // 1) fp32 -> bf16 converts
  cvt_bf16<<<dim3(1024), 256, 0, stream>>>(x, xb, (int)(NBH / 8));
  cvt_bf16<<<dim3(384), 256, 0, stream>>>(w_in, winb, (int)(3 * Ee * Ee / 8));
  cvt_bf16<<<dim3(128), 256, 0, stream>>>(w_out, woutb, (int)(Ee * Ee / 8));
  // 2) QKV projection (MFMA); V written transposed
  qkv_mm<<<dim3(12, 128), 256, 0, stream>>>(xb, winb, b_in, Q, Kb, Vtb);
  // 3) fused attention: scores + softmax + att store + PV (no LDS)
  attn_fused<<<dim3(8, 256), 256, 0, stream>>>(Q, Kb, Vtb, att, Zb);
  // 4) out projection + bias + residual (MFMA)
  out_mm<<<dim3(4, 128), 256, 0, stream>>>(Zb, woutb, b_out, x, y);
  // 5) LayerNorm in place
  ln_kernel<<<dim3(16384), 128, 0, stream>>>(y, gamma, beta, y);
}

// Round 4
// 248.967 us; speedup vs baseline: 1.1703x; 1.1703x over previous
//
#include <hip/hip_runtime.h>
#include <hip/hip_bf16.h>
#include <stdint.h>

#define Bb 32
#define Ss 512
#define Ee 512
#define Hh 8
#define Dd 64
#define EPSf 1e-5f

typedef __attribute__((ext_vector_type(8))) unsigned short ushort8_t;
typedef __attribute__((ext_vector_type(4))) unsigned short ushort4_t;
typedef __attribute__((ext_vector_type(4))) float f32x4;
typedef __attribute__((ext_vector_type(4))) unsigned int uint4_t;
typedef __attribute__((ext_vector_type(8))) __bf16 bf16x8;

union U8cast { ushort8_t u; bf16x8 b; uint4_t w; };
__device__ __forceinline__ bf16x8 as_bf16x8(ushort8_t u) { U8cast c; c.u = u; return c.b; }
__device__ __forceinline__ bf16x8 words_bf16x8(unsigned int w0, unsigned int w1,
                                               unsigned int w2, unsigned int w3) {
  U8cast c; c.w = (uint4_t){w0, w1, w2, w3}; return c.b;
}

__device__ __forceinline__ unsigned short f2bf(float f) {
  __bf16 b = (__bf16)f;                 // RNE fptrunc
  return __builtin_bit_cast(unsigned short, b);
}
__device__ __forceinline__ unsigned int pack2bf(float lo, float hi) {
  return ((unsigned int)f2bf(hi) << 16) | f2bf(lo);
}
__device__ __forceinline__ float bf_lo(unsigned int u) {
  union { unsigned int i; float f; } x; x.i = u << 16; return x.f;
}
__device__ __forceinline__ float bf_hi(unsigned int u) {
  union { unsigned int i; float f; } x; x.i = u & 0xffff0000u; return x.f;
}

__device__ __forceinline__ f32x4 mfma16(bf16x8 a, bf16x8 b, f32x4 c) {
  return __builtin_amdgcn_mfma_f32_16x16x32_bf16(a, b, c, 0, 0, 0);
}

__device__ __forceinline__ void async16(const unsigned short* g, unsigned short* l) {
  __builtin_amdgcn_global_load_lds(
      (const __attribute__((address_space(1))) void*)g,
      (__attribute__((address_space(3))) void*)l, 16, 0, 0);
}

// ---------------- fp32 -> bf16 convert ----------------
__global__ __launch_bounds__(256) void cvt_bf16(const float* __restrict__ src,
                                                unsigned short* __restrict__ dst, int n8) {
  int i = blockIdx.x * 256 + threadIdx.x;
  int stride = gridDim.x * 256;
  for (; i < n8; i += stride) {
    float4 v0 = ((const float4*)src)[2 * i];
    float4 v1 = ((const float4*)src)[2 * i + 1];
    ushort8_t o;
    o[0] = f2bf(v0.x); o[1] = f2bf(v0.y); o[2] = f2bf(v0.z); o[3] = f2bf(v0.w);
    o[4] = f2bf(v1.x); o[5] = f2bf(v1.y); o[6] = f2bf(v1.z); o[7] = f2bf(v1.w);
    ((ushort8_t*)dst)[i] = o;
  }
}

// ---------------- QKV projection: MFMA bf16 ----------------
// C[m][n] = sum_k Xb[m][k] * Wb[n][k] + bin[n];  M=16384, N=1536, K=512
// scatter: Q,K -> [B*H][S][D]; V -> Vt [B*H][D][S] (transposed, packed 8B stores)
__global__ __launch_bounds__(256) void qkv_mm(
    const unsigned short* __restrict__ Xb, const unsigned short* __restrict__ Wb,
    const float* __restrict__ bin,
    unsigned short* __restrict__ Qo, unsigned short* __restrict__ Ko,
    unsigned short* __restrict__ Vto) {
  __shared__ unsigned short As[128 * 64];
  __shared__ unsigned short Bs[128 * 64];
  const int tid = threadIdx.x;
  const int w = tid >> 6, l = tid & 63;
  const int lr = l & 15, lg = l >> 4;
  const int m0 = blockIdx.y * 128, n0 = blockIdx.x * 128;
  const int wm = (w >> 1) * 64, wn = (w & 1) * 64;
  f32x4 acc[4][4];
#pragma unroll
  for (int i = 0; i < 4; ++i)
#pragma unroll
    for (int j = 0; j < 4; ++j) acc[i][j] = (f32x4){0.f, 0.f, 0.f, 0.f};

  for (int k0 = 0; k0 < 512; k0 += 64) {
#pragma unroll
    for (int i = 0; i < 4; ++i) {
      int ci = (w * 4 + i) * 64 + l;         // 16B-chunk index
      int row = ci >> 3, kc = ci & 7;
      int gkc = kc ^ (row & 7);
      async16(Xb + (size_t)(m0 + row) * 512 + k0 + gkc * 8, &As[(w * 4 + i) * 512]);
      async16(Wb + (size_t)(n0 + row) * 512 + k0 + gkc * 8, &Bs[(w * 4 + i) * 512]);
    }
    __syncthreads();
#pragma unroll
    for (int ks = 0; ks < 2; ++ks) {
      bf16x8 af[4], bfr[4];
#pragma unroll
      for (int mf = 0; mf < 4; ++mf) {
        int row = wm + mf * 16 + lr;
        int gc = ks * 4 + lg;
        af[mf] = as_bf16x8(*(const ushort8_t*)&As[row * 64 + ((gc ^ (row & 7)) * 8)]);
      }
#pragma unroll
      for (int nf = 0; nf < 4; ++nf) {
        int row = wn + nf * 16 + lr;
        int gc = ks * 4 + lg;
        bfr[nf] = as_bf16x8(*(const ushort8_t*)&Bs[row * 64 + ((gc ^ (row & 7)) * 8)]);
      }
#pragma unroll
      for (int mf = 0; mf < 4; ++mf)
#pragma unroll
        for (int nf = 0; nf < 4; ++nf) acc[mf][nf] = mfma16(af[mf], bfr[nf], acc[mf][nf]);
    }
    __syncthreads();
  }

#pragma unroll
  for (int nf = 0; nf < 4; ++nf) {
    int n = n0 + wn + nf * 16 + lr;
    float bias = bin[n];
    int which = n >> 9, e = n & 511, h = e >> 6, d = e & 63;
#pragma unroll
    for (int mf = 0; mf < 4; ++mf) {
      int mbase = m0 + wm + mf * 16 + lg * 4;
      int bb = mbase >> 9, s0 = mbase & 511;
      if (which == 2) {
        ushort4_t vv;
#pragma unroll
        for (int r = 0; r < 4; ++r) vv[r] = f2bf(acc[mf][nf][r] + bias);
        *(ushort4_t*)&Vto[(((size_t)(bb * Hh + h)) * Dd + d) * Ss + s0] = vv;
      } else {
        unsigned short* dst = (which == 0) ? Qo : Ko;
#pragma unroll
        for (int r = 0; r < 4; ++r)
          dst[(((size_t)(bb * Hh + h)) * Ss + s0 + r) * Dd + d] = f2bf(acc[mf][nf][r] + bias);
      }
    }
  }
}

// ---------------- fused attention (register-only, chunked online softmax) ----
// block: one (b,h), 64 q-rows; 4 waves x 16 q-rows each. No LDS.
// Swapped QK^T: C=P[k][q]. K-rows permuted so frag pair (2c,2c+1) holds the
// 8 consecutive k PV's B-operand needs per lane. P kept as packed bf16 (64 regs).
__global__ __launch_bounds__(256, 2) void attn_fused(
    const unsigned short* __restrict__ Q, const unsigned short* __restrict__ K,
    const unsigned short* __restrict__ Vt, float* __restrict__ att,
    unsigned short* __restrict__ Zb) {
  const int tid = threadIdx.x;
  const int w = tid >> 6, l = tid & 63;
  const int lr = l & 15, lg = l >> 4;
  // XCD-friendly decode: all 8 q-blocks of a (b,h) land on one XCD, adjacent in time
  const int id = blockIdx.x;
  const int bh = (id >> 6) * 8 + (id & 7);
  const int m0 = ((id >> 3) & 7) * 64;
  const int b = bh >> 3, h = bh & 7;
  const unsigned short* Qp = Q + (size_t)bh * Ss * Dd;
  const unsigned short* Kp = K + (size_t)bh * Ss * Dd;
  const unsigned short* Vp = Vt + (size_t)bh * Dd * Ss;   // [64][512]

  const int q0g = m0 + w * 16;
  // Q as B-operand: lane holds Q[q0g+lr][lg*8+j], two d-halves
  bf16x8 bq0 = as_bf16x8(*(const ushort8_t*)(Qp + (size_t)(q0g + lr) * Dd + lg * 8));
  bf16x8 bq1 = as_bf16x8(*(const ushort8_t*)(Qp + (size_t)(q0g + lr) * Dd + 32 + lg * 8));

  // permuted K-row base: frag nf=(2c+odd), A-row lr -> K row 32c+4odd+krow;
  // C elem (lg,r) -> k = 32c + 8lg + 4odd + r
  const int krow = 8 * (lr >> 2) + (lr & 3);

  unsigned int pp[64];                       // packed bf16 P (unnormalized)
  f32x4 o[4];
#pragma unroll
  for (int df = 0; df < 4; ++df) o[df] = (f32x4){0.f, 0.f, 0.f, 0.f};
  float m_run = 0.f, ssum = 0.f;

#pragma unroll
  for (int C = 0; C < 4; ++C) {
    // ---- QK^T for 128 keys (8 frags)
    f32x4 s8[8];
#pragma unroll
    for (int j = 0; j < 8; ++j) {
      int nf = 8 * C + j;
      int c = nf >> 1, odd = nf & 1;
      int row = 32 * c + 4 * odd + krow;
      bf16x8 ak0 = as_bf16x8(*(const ushort8_t*)(Kp + (size_t)row * Dd + lg * 8));
      bf16x8 ak1 = as_bf16x8(*(const ushort8_t*)(Kp + (size_t)row * Dd + 32 + lg * 8));
      f32x4 z = (f32x4){0.f, 0.f, 0.f, 0.f};
      z = mfma16(ak0, bq0, z);
      s8[j] = mfma16(ak1, bq1, z);
    }
    // ---- chunk max (per q=lr, consistent across lg lanes)
    float cm = s8[0][0];
#pragma unroll
    for (int j = 0; j < 8; ++j)
#pragma unroll
      for (int r = 0; r < 4; ++r) cm = fmaxf(cm, s8[j][r]);
    cm = fmaxf(cm, __shfl_xor(cm, 16));
    cm = fmaxf(cm, __shfl_xor(cm, 32));
    if (C == 0) {
      m_run = cm;
    } else if (cm - m_run > 64.f) {          // defer-rescale threshold (8 post-scale)
      float factor = __expf((m_run - cm) * 0.125f);
      ssum *= factor;
#pragma unroll
      for (int df = 0; df < 4; ++df) o[df] *= factor;
#pragma unroll
      for (int t = 0; t < 16 * C; ++t)
        pp[t] = pack2bf(bf_lo(pp[t]) * factor, bf_hi(pp[t]) * factor);
      m_run = cm;
    }
    // ---- exp (f32), accumulate denom, pack to bf16
#pragma unroll
    for (int j = 0; j < 8; ++j) {
      int nf = 8 * C + j;
      float p0 = __expf((s8[j][0] - m_run) * 0.125f);
      float p1 = __expf((s8[j][1] - m_run) * 0.125f);
      float p2 = __expf((s8[j][2] - m_run) * 0.125f);
      float p3 = __expf((s8[j][3] - m_run) * 0.125f);
      ssum += (p0 + p1) + (p2 + p3);
      pp[2 * nf] = pack2bf(p0, p1);
      pp[2 * nf + 1] = pack2bf(p2, p3);
    }
    // ---- PV for this chunk's 4 pair-chunks (V loads overlap next K loads)
#pragma unroll
    for (int cc = 0; cc < 4; ++cc) {
      int c2 = 4 * C + cc;
      bf16x8 bp = words_bf16x8(pp[4 * c2], pp[4 * c2 + 1], pp[4 * c2 + 2], pp[4 * c2 + 3]);
#pragma unroll
      for (int df = 0; df < 4; ++df) {
        bf16x8 av = as_bf16x8(
            *(const ushort8_t*)(Vp + (size_t)(df * 16 + lr) * Ss + 32 * c2 + lg * 8));
        o[df] = mfma16(av, bp, o[df]);
      }
    }
  }

  // ---- denominator across lg halves
  ssum += __shfl_xor(ssum, 16);
  ssum += __shfl_xor(ssum, 32);
  float inv = 1.0f / ssum;

  // ---- write att_w: lane covers k = 32c2+8lg .. +7 (fp32, one pass)
  float* attp = att + (size_t)bh * Ss * Ss + (size_t)(q0g + lr) * Ss;
#pragma unroll
  for (int c2 = 0; c2 < 16; ++c2) {
    f32x4 v0, v1;
    v0[0] = bf_lo(pp[4 * c2]) * inv;     v0[1] = bf_hi(pp[4 * c2]) * inv;
    v0[2] = bf_lo(pp[4 * c2 + 1]) * inv; v0[3] = bf_hi(pp[4 * c2 + 1]) * inv;
    v1[0] = bf_lo(pp[4 * c2 + 2]) * inv; v1[1] = bf_hi(pp[4 * c2 + 2]) * inv;
    v1[2] = bf_lo(pp[4 * c2 + 3]) * inv; v1[3] = bf_hi(pp[4 * c2 + 3]) * inv;
    *(f32x4*)(attp + 32 * c2 + 8 * lg) = v0;
    *(f32x4*)(attp + 32 * c2 + 8 * lg + 4) = v1;
  }

  // ---- Z (merged heads) bf16: C[d][q], scale by inv; lane writes 8B
  unsigned short* zrow = Zb + ((size_t)(b * Ss) + q0g + lr) * Ee + h * Dd;
#pragma unroll
  for (int df = 0; df < 4; ++df) {
    ushort4_t zz;
    zz[0] = f2bf(o[df][0] * inv); zz[1] = f2bf(o[df][1] * inv);
    zz[2] = f2bf(o[df][2] * inv); zz[3] = f2bf(o[df][3] * inv);
    *(ushort4_t*)(zrow + df * 16 + lg * 4) = zz;
  }
}

// ---------------- out projection: MFMA bf16 + bias + residual ----------------
// y[m][n] = sum_k Zb[m][k]*Wout[n][k] + bout[n] + X[m][n]; M=16384, N=512, K=512
__global__ __launch_bounds__(256) void out_mm(
    const unsigned short* __restrict__ Zb, const unsigned short* __restrict__ Wb,
    const float* __restrict__ bout, const float* __restrict__ X,
    float* __restrict__ Y) {
  __shared__ unsigned short As[128 * 64];
  __shared__ unsigned short Bs[128 * 64];
  const int tid = threadIdx.x;
  const int w = tid >> 6, l = tid & 63;
  const int lr = l & 15, lg = l >> 4;
  const int m0 = blockIdx.y * 128, n0 = blockIdx.x * 128;
  const int wm = (w >> 1) * 64, wn = (w & 1) * 64;
  f32x4 acc[4][4];
#pragma unroll
  for (int i = 0; i < 4; ++i)
#pragma unroll
    for (int j = 0; j < 4; ++j) acc[i][j] = (f32x4){0.f, 0.f, 0.f, 0.f};

  for (int k0 = 0; k0 < 512; k0 += 64) {
#pragma unroll
    for (int i = 0; i < 4; ++i) {
      int ci = (w * 4 + i) * 64 + l;
      int row = ci >> 3, kc = ci & 7;
      int gkc = kc ^ (row & 7);
      async16(Zb + (size_t)(m0 + row) * 512 + k0 + gkc * 8, &As[(w * 4 + i) * 512]);
      async16(Wb + (size_t)(n0 + row) * 512 + k0 + gkc * 8, &Bs[(w * 4 + i) * 512]);
    }
    __syncthreads();
#pragma unroll
    for (int ks = 0; ks < 2; ++ks) {
      bf16x8 af[4], bfr[4];
#pragma unroll
      for (int mf = 0; mf < 4; ++mf) {
        int row = wm + mf * 16 + lr;
        int gc = ks * 4 + lg;
        af[mf] = as_bf16x8(*(const ushort8_t*)&As[row * 64 + ((gc ^ (row & 7)) * 8)]);
      }
#pragma unroll
      for (int nf = 0; nf < 4; ++nf) {
        int row = wn + nf * 16 + lr;
        int gc = ks * 4 + lg;
        bfr[nf] = as_bf16x8(*(const ushort8_t*)&Bs[row * 64 + ((gc ^ (row & 7)) * 8)]);
      }
#pragma unroll
      for (int mf = 0; mf < 4; ++mf)
#pragma unroll
        for (int nf = 0; nf < 4; ++nf) acc[mf][nf] = mfma16(af[mf], bfr[nf], acc[mf][nf]);
    }
    __syncthreads();
  }

#pragma unroll
  for (int nf = 0; nf < 4; ++nf) {
    int n = n0 + wn + nf * 16 + lr;
    float bias = bout[n];
#pragma unroll
    for (int mf = 0; mf < 4; ++mf) {
#pragma unroll
      for (int r = 0; r < 4; ++r) {
        int m = m0 + wm + mf * 16 + lg * 4 + r;
        Y[(size_t)m * 512 + n] = acc[mf][nf][r] + bias + X[(size_t)m * 512 + n];
      }
    }
  }
}

// ---------------- LayerNorm (in place on y region) ----------------
__global__ __launch_bounds__(128) void ln_kernel(
    const float* __restrict__ Z2, const float* __restrict__ gamma,
    const float* __restrict__ beta, float* __restrict__ Y) {
  const int row = blockIdx.x;
  const int t = threadIdx.x;
  float4 v = *(const float4*)(Z2 + (size_t)row * 512 + t * 4);
  float sum = v.x + v.y + v.z + v.w;
  float sq = v.x * v.x + v.y * v.y + v.z * v.z + v.w * v.w;
#pragma unroll
  for (int off = 32; off; off >>= 1) {
    sum += __shfl_xor(sum, off);
    sq += __shfl_xor(sq, off);
  }
  __shared__ float s0[2], s1[2];
  int wv = t >> 6;
  if ((t & 63) == 0) { s0[wv] = sum; s1[wv] = sq; }
  __syncthreads();
  sum = s0[0] + s0[1];
  sq = s1[0] + s1[1];
  float mu = sum * (1.0f / 512.0f);
  float var = sq * (1.0f / 512.0f) - mu * mu;
  float rs = rsqrtf(var + EPSf);
  float4 g = *(const float4*)(gamma + t * 4);
  float4 be = *(const float4*)(beta + t * 4);
  float4 o;
  o.x = (v.x - mu) * rs * g.x + be.x;
  o.y = (v.y - mu) * rs * g.y + be.y;
  o.z = (v.z - mu) * rs * g.z + be.z;
  o.w = (v.w - mu) * rs * g.w + be.w;
  *(float4*)(Y + (size_t)row * 512 + t * 4) = o;
}

extern "C" void kernel_launch(void* const* d_in, const int* in_sizes, int n_in,
                              void* d_out, int out_size, void* d_ws, size_t ws_size,
                              hipStream_t stream) {
  const float* x = (const float*)d_in[0];
  const float* w_in = (const float*)d_in[1];
  const float* b_in = (const float*)d_in[2];
  const float* w_out = (const float*)d_in[3];
  const float* b_out = (const float*)d_in[4];
  const float* gamma = (const float*)d_in[5];
  const float* beta = (const float*)d_in[6];

  float* y = (float*)d_out;                                   // [B,S,E] fp32
  float* att = (float*)d_out + (size_t)Bb * Ss * Ee;          // [B,H,S,S] fp32

  char* ws = (char*)d_ws;
  const size_t NBH = (size_t)Bb * Hh * Ss * Dd;               // 8.39M elems
  unsigned short* Q     = (unsigned short*)ws;                // 16.78 MB
  unsigned short* Kb    = Q + NBH;
  unsigned short* Vtb   = Kb + NBH;                           // [BH][D][S]
  unsigned short* xb    = Vtb + NBH;                          // [16384][512] bf16
  unsigned short* Zb    = xb;                                 // alias: xb dead after qkv_mm
  unsigned short* winb  = xb + NBH;                           // [1536][512]
  unsigned short* woutb = winb + (size_t)3 * Ee * Ee;         // [512][512]

  // 1) fp32 -> bf16 converts
  cvt_bf16<<<dim3(1024), 256, 0, stream>>>(x, xb, (int)(NBH / 8));
  cvt_bf16<<<dim3(384), 256, 0, stream>>>(w_in, winb, (int)(3 * Ee * Ee / 8));
  cvt_bf16<<<dim3(128), 256, 0, stream>>>(w_out, woutb, (int)(Ee * Ee / 8));
  // 2) QKV projection (MFMA); V written transposed (packed stores)
  qkv_mm<<<dim3(12, 128), 256, 0, stream>>>(xb, winb, b_in, Q, Kb, Vtb);
  // 3) fused attention: scores + online softmax + att store + PV (no LDS)
  attn_fused<<<dim3(2048), 256, 0, stream>>>(Q, Kb, Vtb, att, Zb);
  // 4) out projection + bias + residual (MFMA)
  out_mm<<<dim3(4, 128), 256, 0, stream>>>(Zb, woutb, b_out, x, y);
  // 5) LayerNorm in place
  ln_kernel<<<dim3(16384), 128, 0, stream>>>(y, gamma, beta, y);
}